// Round 2
// baseline (1046.249 us; speedup 1.0000x reference)
//
#include <hip/hip_runtime.h>
#include <hip/hip_bf16.h>

typedef __attribute__((ext_vector_type(8))) short short8;
typedef __attribute__((ext_vector_type(4))) short short4v;
typedef __attribute__((ext_vector_type(4))) float floatx4;

#define N_CELLS  500000
#define B_SAMP   512
#define D_X      128
#define D_Z      32
#define H_DIM    256
#define D_OUT    16

#define M_TILE   64
#define NT       7813          // ceil(500000/64)
#define NPBLK    512           // persistent blocks: 2 per CU
#define LDA      136           // Xp LDS row stride (bf16): 272B, 2-way banks
#define LDH      264           // H LDS row stride (bf16): 528B, 2-way banks
#define SP_LD    20            // GEMM3 partial row stride (f32)

#define NREP     64

// workspace layout (bytes), 16B aligned
#define OFF_W1P   0            // 16*4*512*2   = 65536
#define OFF_W2P   65536        // 16*8*512*2   = 131072
#define OFF_W3P   196608       // 1*8*512*2    = 8192
#define OFF_ZW    204800       // 512*256*4    = 524288
#define OFF_ACC   729088       // 64*8192*4    = 2097152
#define OFF_CNT   2826240      // 64*512*4     = 131072
#define OFF_C2S   2957312      // 500000*4     = 2000000  (end ~4.96 MB)

#define ZERO_BLKS 2176         // 557056 floats (accs+cnts contiguous)
#define W1_BLKS   128
#define W2_BLKS   256
#define W3_BLKS   16
#define ZW_BLKS   512
#define C2S_BLKS  1954

__device__ __forceinline__ short bfb(float x) {
    union { __hip_bfloat16 h; short s; } u;
    u.h = __float2bfloat16(x);
    return u.s;
}

// prep: zero accumulators; pack W1(K=128 rows, ln2-folded)/W2/W3 into MFMA
// fragment order; ZW1[b][n] = Z[b,:]@W1[128:160,n] + b1[n] (fp32);
// c2s[cell] = sidx[c2b[cell]].
__global__ __launch_bounds__(256)
void prep(const float* __restrict__ W1, const float* __restrict__ b1,
          const float* __restrict__ W2, const float* __restrict__ W3,
          const float* __restrict__ Z,
          const int* __restrict__ c2b, const int* __restrict__ sidx,
          __hip_bfloat16* __restrict__ w1p, __hip_bfloat16* __restrict__ w2p,
          __hip_bfloat16* __restrict__ w3p, float* __restrict__ zw1,
          float* __restrict__ accs, int* __restrict__ c2s) {
    int bid = blockIdx.x;
    int tid = threadIdx.x;
    if (bid < ZERO_BLKS) { accs[bid * 256 + tid] = 0.0f; return; }
    bid -= ZERO_BLKS;
    if (bid < W1_BLKS + W2_BLKS + W3_BLKS) {
        const float* W; __hip_bfloat16* dst; int N, kS, idx; float scale;
        if (bid < W1_BLKS) {
            idx = bid * 256 + tid; W = W1; dst = w1p; N = H_DIM; kS = 4;
            scale = 0.6931471805599453f;          // ln2: staging uses log2
        } else if (bid < W1_BLKS + W2_BLKS) {
            idx = (bid - W1_BLKS) * 256 + tid; W = W2; dst = w2p; N = H_DIM; kS = 8;
            scale = 1.0f;
        } else {
            idx = (bid - W1_BLKS - W2_BLKS) * 256 + tid; W = W3; dst = w3p; N = D_OUT; kS = 8;
            scale = 1.0f;
        }
        int j = idx & 7;
        int L = (idx >> 3) & 63;
        int s = (idx >> 9) % kS;
        int t = idx / (kS << 9);
        int k = s * 32 + ((L >> 4) << 3) + j;
        int n = t * 16 + (L & 15);
        dst[idx] = __float2bfloat16(W[(size_t)k * N + n] * scale);
        return;
    }
    bid -= W1_BLKS + W2_BLKS + W3_BLKS;
    if (bid < ZW_BLKS) {
        int s = bid;
        float a = b1[tid];
        const float* zr = Z + (size_t)s * D_Z;
        const float* wr = W1 + (size_t)D_X * H_DIM + tid;
#pragma unroll 8
        for (int k = 0; k < D_Z; ++k) a += zr[k] * wr[(size_t)k * H_DIM];
        zw1[(size_t)s * H_DIM + tid] = a;
        return;
    }
    bid -= ZW_BLKS;
    int i = bid * 256 + tid;
    if (i < N_CELLS) c2s[i] = sidx[c2b[i]];
}

// Persistent pipelined MLP: 512 blocks x 512 threads (8 waves: 2M x 4N).
// Per tile: stage Xp(bf16,log2) -> GEMM1(K=128)+ZW epilogue -> GEMM2(in-place)
// -> GEMM3(8 waves, K-split) -> staged coalesced atomics. Next tile's X is
// prefetched into registers right after staging, hiding HBM latency under
// the three GEMMs.
__global__ __launch_bounds__(512, 4)
void fused_mlp(const float* __restrict__ X, const int* __restrict__ c2b,
               const int* __restrict__ c2s, const float* __restrict__ b2,
               const float* __restrict__ b3,
               const __hip_bfloat16* __restrict__ w1p,
               const __hip_bfloat16* __restrict__ w2p,
               const __hip_bfloat16* __restrict__ w3p,
               const float* __restrict__ zw1,
               float* __restrict__ accs, float* __restrict__ cnts) {
    __shared__ __align__(16) short sX[M_TILE * LDA];   // Xp; aliased as GEMM3 partials
    __shared__ short sH[M_TILE][LDH];                  // H0 then H1 (in-place)
    __shared__ int sCB[M_TILE];
    __shared__ int sSI[M_TILE];
    short (*xp)[LDA] = (short (*)[LDA])sX;
    float (*sP)[M_TILE][SP_LD] = (float (*)[M_TILE][SP_LD])sX;

    const int tid = threadIdx.x;
    const int w   = tid >> 6;     // wave 0..7
    const int L   = tid & 63;
    const int q   = L >> 4;
    const int ln  = L & 15;
    const int wm  = w >> 2;       // cell-half
    const int wn  = w & 3;        // N-quarter

    float4 xr[4];
    int cb = 0, si = 0;

    int t = blockIdx.x;
    {   // prefetch first tile
        int base = t * M_TILE;
#pragma unroll
        for (int i = 0; i < 4; ++i) {
            int idx = tid + i * 512;
            int gr = base + (idx >> 5); if (gr >= N_CELLS) gr = N_CELLS - 1;
            xr[i] = *(const float4*)(X + (size_t)gr * D_X + (idx & 31) * 4);
        }
        if ((tid & 7) == 0) {
            int gr = base + (tid >> 3); if (gr >= N_CELLS) gr = N_CELLS - 1;
            cb = c2b[gr];
            si = c2s[gr];
        }
    }

    for (; t < NT; t += NPBLK) {
        const int base = t * M_TILE;

        // ---- stage Xp(t) from prefetched regs ----
#pragma unroll
        for (int i = 0; i < 4; ++i) {
            int idx = tid + i * 512;
            int row = idx >> 5, c4 = idx & 31;
            short4v pk;
            pk.x = bfb(__log2f(1.0f + xr[i].x));
            pk.y = bfb(__log2f(1.0f + xr[i].y));
            pk.z = bfb(__log2f(1.0f + xr[i].z));
            pk.w = bfb(__log2f(1.0f + xr[i].w));
            *(short4v*)&xp[row][c4 * 4] = pk;
        }
        if ((tid & 7) == 0) { sCB[tid >> 3] = cb; sSI[tid >> 3] = si; }
        __syncthreads();                                            // b1

        // ---- issue prefetch of tile t+NPBLK (independent loads) ----
        if (t + NPBLK < NT) {
            int nb = (t + NPBLK) * M_TILE;
#pragma unroll
            for (int i = 0; i < 4; ++i) {
                int idx = tid + i * 512;
                int gr = nb + (idx >> 5); if (gr >= N_CELLS) gr = N_CELLS - 1;
                xr[i] = *(const float4*)(X + (size_t)gr * D_X + (idx & 31) * 4);
            }
            if ((tid & 7) == 0) {
                int gr = nb + (tid >> 3); if (gr >= N_CELLS) gr = N_CELLS - 1;
                cb = c2b[gr];
                si = c2s[gr];
            }
        }

        // ---- GEMM1: relu(logX @ W1x + ZW1[cb]) -> sH ----
        int cb0 = sCB[wm * 32 + ln];
        int cb1 = sCB[wm * 32 + 16 + ln];
        float4 zwa[4], zwb[4];
#pragma unroll
        for (int nt = 0; nt < 4; ++nt) {
            zwa[nt] = *(const float4*)(zw1 + (size_t)cb0 * H_DIM + wn * 64 + nt * 16 + q * 4);
            zwb[nt] = *(const float4*)(zw1 + (size_t)cb1 * H_DIM + wn * 64 + nt * 16 + q * 4);
        }
        floatx4 acc[2][4];
#pragma unroll
        for (int mt = 0; mt < 2; ++mt)
#pragma unroll
            for (int nt = 0; nt < 4; ++nt)
                acc[mt][nt] = (floatx4){0.f, 0.f, 0.f, 0.f};
#pragma unroll
        for (int s = 0; s < 4; ++s) {
            short8 x0 = *(const short8*)&xp[wm * 32 + ln][s * 32 + q * 8];
            short8 x1 = *(const short8*)&xp[wm * 32 + 16 + ln][s * 32 + q * 8];
#pragma unroll
            for (int nt = 0; nt < 4; ++nt) {
                short8 wf = *(const short8*)(w1p + (size_t)(((((wn * 4 + nt) * 4) + s) << 6) + L) * 8);
                acc[0][nt] = __builtin_amdgcn_mfma_f32_16x16x32_bf16(wf, x0, acc[0][nt], 0, 0, 0);
                acc[1][nt] = __builtin_amdgcn_mfma_f32_16x16x32_bf16(wf, x1, acc[1][nt], 0, 0, 0);
            }
        }
#pragma unroll
        for (int nt = 0; nt < 4; ++nt) {
            short4v p0, p1;
            p0.x = bfb(fmaxf(acc[0][nt][0] + zwa[nt].x, 0.f));
            p0.y = bfb(fmaxf(acc[0][nt][1] + zwa[nt].y, 0.f));
            p0.z = bfb(fmaxf(acc[0][nt][2] + zwa[nt].z, 0.f));
            p0.w = bfb(fmaxf(acc[0][nt][3] + zwa[nt].w, 0.f));
            p1.x = bfb(fmaxf(acc[1][nt][0] + zwb[nt].x, 0.f));
            p1.y = bfb(fmaxf(acc[1][nt][1] + zwb[nt].y, 0.f));
            p1.z = bfb(fmaxf(acc[1][nt][2] + zwb[nt].z, 0.f));
            p1.w = bfb(fmaxf(acc[1][nt][3] + zwb[nt].w, 0.f));
            *(short4v*)&sH[wm * 32 + ln][wn * 64 + nt * 16 + q * 4] = p0;
            *(short4v*)&sH[wm * 32 + 16 + ln][wn * 64 + nt * 16 + q * 4] = p1;
        }
        __syncthreads();                                            // b2

        // ---- GEMM2: relu(H0 @ W2 + b2), in-place on sH ----
#pragma unroll
        for (int nt = 0; nt < 4; ++nt) {
            float4 bv = *(const float4*)(b2 + wn * 64 + nt * 16 + q * 4);
            acc[0][nt] = (floatx4){bv.x, bv.y, bv.z, bv.w};
            acc[1][nt] = acc[0][nt];
        }
#pragma unroll
        for (int s = 0; s < 8; ++s) {
            short8 x0 = *(const short8*)&sH[wm * 32 + ln][s * 32 + q * 8];
            short8 x1 = *(const short8*)&sH[wm * 32 + 16 + ln][s * 32 + q * 8];
#pragma unroll
            for (int nt = 0; nt < 4; ++nt) {
                short8 wf = *(const short8*)(w2p + (size_t)(((((wn * 4 + nt) * 8) + s) << 6) + L) * 8);
                acc[0][nt] = __builtin_amdgcn_mfma_f32_16x16x32_bf16(wf, x0, acc[0][nt], 0, 0, 0);
                acc[1][nt] = __builtin_amdgcn_mfma_f32_16x16x32_bf16(wf, x1, acc[1][nt], 0, 0, 0);
            }
        }
        __syncthreads();                                            // b3: reads done
#pragma unroll
        for (int nt = 0; nt < 4; ++nt) {
            short4v p0, p1;
            p0.x = bfb(fmaxf(acc[0][nt][0], 0.f));
            p0.y = bfb(fmaxf(acc[0][nt][1], 0.f));
            p0.z = bfb(fmaxf(acc[0][nt][2], 0.f));
            p0.w = bfb(fmaxf(acc[0][nt][3], 0.f));
            p1.x = bfb(fmaxf(acc[1][nt][0], 0.f));
            p1.y = bfb(fmaxf(acc[1][nt][1], 0.f));
            p1.z = bfb(fmaxf(acc[1][nt][2], 0.f));
            p1.w = bfb(fmaxf(acc[1][nt][3], 0.f));
            *(short4v*)&sH[wm * 32 + ln][wn * 64 + nt * 16 + q * 4] = p0;
            *(short4v*)&sH[wm * 32 + 16 + ln][wn * 64 + nt * 16 + q * 4] = p1;
        }
        __syncthreads();                                            // b4

        // ---- GEMM3: 8 waves = 4 cell-groups x 2 K-halves ----
        {
            int g  = w & 3;        // 16-cell group
            int kh = w >> 2;       // K half
            floatx4 a3 = (floatx4){0.f, 0.f, 0.f, 0.f};
#pragma unroll
            for (int ss = 0; ss < 4; ++ss) {
                int s = kh * 4 + ss;
                short8 hv = *(const short8*)&sH[g * 16 + ln][s * 32 + q * 8];
                short8 wf = *(const short8*)(w3p + (size_t)(((s) << 6) + L) * 8);
                a3 = __builtin_amdgcn_mfma_f32_16x16x32_bf16(wf, hv, a3, 0, 0, 0);
            }
#pragma unroll
            for (int r = 0; r < 4; ++r)
                sP[kh][g * 16 + ln][q * 4 + r] = a3[r];
        }
        __syncthreads();                                            // b5

        // ---- combine K-halves + b3, coalesced atomics ----
        {
            int rep = ((t >> 9) + t) & (NREP - 1);
            float* accR = accs + (size_t)rep * (B_SAMP * D_OUT);
            float* cntR = cnts + (size_t)rep * B_SAMP;
#pragma unroll
            for (int i = 0; i < 2; ++i) {
                int idx = tid + i * 512;      // 64 cells x 16 outs
                int m = idx >> 4, n = idx & 15;
                int cell = base + m;
                if (cell < N_CELLS) {
                    float v = sP[0][m][n] + sP[1][m][n] + b3[n];
                    int so = sSI[m];
                    atomicAdd(&accR[(size_t)so * D_OUT + n], v);
                    if (n == 0) atomicAdd(&cntR[so], 1.0f);
                }
            }
        }
        __syncthreads();                                            // b6
    }
}

__global__ __launch_bounds__(256)
void finalize(const float* __restrict__ accs, const float* __restrict__ cnts,
              float* __restrict__ out) {
    int o = blockIdx.x * blockDim.x + threadIdx.x;   // 0..8191
    int s = o >> 4;
    float sum = 0.f, cnt = 0.f;
#pragma unroll 8
    for (int r = 0; r < NREP; ++r) {
        sum += accs[(size_t)r * (B_SAMP * D_OUT) + o];
        cnt += cnts[(size_t)r * B_SAMP + s];
    }
    out[o] = sum / fmaxf(cnt, 1.0f);
}

extern "C" void kernel_launch(void* const* d_in, const int* in_sizes, int n_in,
                              void* d_out, int out_size, void* d_ws, size_t ws_size,
                              hipStream_t stream) {
    const float* X   = (const float*)d_in[0];
    const float* Z   = (const float*)d_in[1];
    const float* W1  = (const float*)d_in[2];
    const float* b1  = (const float*)d_in[3];
    const float* W2  = (const float*)d_in[4];
    const float* b2  = (const float*)d_in[5];
    const float* W3  = (const float*)d_in[6];
    const float* b3  = (const float*)d_in[7];
    const int*   c2b = (const int*)d_in[8];
    const int*   sidx= (const int*)d_in[9];

    char* ws = (char*)d_ws;
    __hip_bfloat16* w1p = (__hip_bfloat16*)(ws + OFF_W1P);
    __hip_bfloat16* w2p = (__hip_bfloat16*)(ws + OFF_W2P);
    __hip_bfloat16* w3p = (__hip_bfloat16*)(ws + OFF_W3P);
    float* zw1  = (float*)(ws + OFF_ZW);
    float* accs = (float*)(ws + OFF_ACC);
    float* cnts = (float*)(ws + OFF_CNT);
    int*   c2s  = (int*)(ws + OFF_C2S);
    float* out  = (float*)d_out;

    prep<<<ZERO_BLKS + W1_BLKS + W2_BLKS + W3_BLKS + ZW_BLKS + C2S_BLKS, 256, 0, stream>>>(
        W1, b1, W2, W3, Z, c2b, sidx, w1p, w2p, w3p, zw1, accs, c2s);

    fused_mlp<<<NPBLK, 512, 0, stream>>>(X, c2b, c2s, b2, b3,
                                         w1p, w2p, w3p, zw1, accs, cnts);
    finalize<<<32, 256, 0, stream>>>(accs, cnts, out);
}

// Round 3
// 525.726 us; speedup vs baseline: 1.9901x; 1.9901x over previous
//
#include <hip/hip_runtime.h>
#include <hip/hip_bf16.h>

typedef __attribute__((ext_vector_type(8))) short short8;
typedef __attribute__((ext_vector_type(4))) short short4v;
typedef __attribute__((ext_vector_type(4))) float floatx4;

#define N_CELLS  500000
#define B_SAMP   512
#define D_X      128
#define D_Z      32
#define H_DIM    256
#define D_OUT    16

#define M_TILE   64
#define NBLK     7813          // ceil(500000/64); last block has 32 valid cells
#define LDA      136           // Xp LDS row stride (bf16)
#define LDH      264           // H LDS row stride (bf16)
#define SP_LD    20            // GEMM3 partial row stride (f32)

#define NREP     64

// workspace layout (bytes), 16B aligned
#define OFF_W1P   0            // 16*4*512*2   = 65536
#define OFF_W2P   65536        // 16*8*512*2   = 131072
#define OFF_W3P   196608       // 1*8*512*2    = 8192
#define OFF_ZW    204800       // 512*256*4    = 524288
#define OFF_ACC   729088       // 64*8192*4    = 2097152
#define OFF_CNT   2826240      // 64*512*4     = 131072
#define OFF_C2S   2957312      // 500000*4     = 2000000

#define W1_BLKS   128
#define W2_BLKS   256
#define W3_BLKS   16
#define ZW_BLKS   512
#define C2S_BLKS  1954

__device__ __forceinline__ short bfb(float x) {
    union { __hip_bfloat16 h; short s; } u;
    u.h = __float2bfloat16(x);
    return u.s;
}

// prep: pack W1(K=128, ln2-folded)/W2/W3 into MFMA fragment order;
// ZW1[b][n] = Z[b,:]@W1[128:160,n] + b1[n]; c2s[cell]=sidx[c2b[cell]];
// counts histogram (MLP-independent) into replicated cnts.
// NOTE: accs/cnts are zeroed by hipMemsetAsync BEFORE this launch (stream order).
__global__ __launch_bounds__(256)
void prep(const float* __restrict__ W1, const float* __restrict__ b1,
          const float* __restrict__ W2, const float* __restrict__ W3,
          const float* __restrict__ Z,
          const int* __restrict__ c2b, const int* __restrict__ sidx,
          __hip_bfloat16* __restrict__ w1p, __hip_bfloat16* __restrict__ w2p,
          __hip_bfloat16* __restrict__ w3p, float* __restrict__ zw1,
          float* __restrict__ cnts, int* __restrict__ c2s) {
    int bid = blockIdx.x;
    int tid = threadIdx.x;
    if (bid < W1_BLKS + W2_BLKS + W3_BLKS) {
        const float* W; __hip_bfloat16* dst; int N, kS, idx; float scale;
        if (bid < W1_BLKS) {
            idx = bid * 256 + tid; W = W1; dst = w1p; N = H_DIM; kS = 4;
            scale = 0.6931471805599453f;          // ln2: staging uses log2
        } else if (bid < W1_BLKS + W2_BLKS) {
            idx = (bid - W1_BLKS) * 256 + tid; W = W2; dst = w2p; N = H_DIM; kS = 8;
            scale = 1.0f;
        } else {
            idx = (bid - W1_BLKS - W2_BLKS) * 256 + tid; W = W3; dst = w3p; N = D_OUT; kS = 8;
            scale = 1.0f;
        }
        int j = idx & 7;
        int L = (idx >> 3) & 63;
        int s = (idx >> 9) % kS;
        int t = idx / (kS << 9);
        int k = s * 32 + ((L >> 4) << 3) + j;
        int n = t * 16 + (L & 15);
        dst[idx] = __float2bfloat16(W[(size_t)k * N + n] * scale);
        return;
    }
    bid -= W1_BLKS + W2_BLKS + W3_BLKS;
    if (bid < ZW_BLKS) {
        int s = bid;
        float a = b1[tid];
        const float* zr = Z + (size_t)s * D_Z;
        const float* wr = W1 + (size_t)D_X * H_DIM + tid;
#pragma unroll 8
        for (int k = 0; k < D_Z; ++k) a += zr[k] * wr[(size_t)k * H_DIM];
        zw1[(size_t)s * H_DIM + tid] = a;
        return;
    }
    bid -= ZW_BLKS;
    int i = bid * 256 + tid;
    if (i < N_CELLS) {
        int si = sidx[c2b[i]];
        c2s[i] = si;
        atomicAdd(&cnts[(size_t)(bid & (NREP - 1)) * B_SAMP + si], 1.0f);
    }
}

// One 64-cell tile per block, 512 threads (8 waves: 2 cell-halves x 4 N-quarters).
// Operand-swapped MFMA (D = mfma(W, cells)): 4 consecutive output features per
// thread. GEMM1 C-init = ZW1 gather (bias + Z-contribution precomputed; gather
// addresses from global c2b so loads issue at kernel entry, hidden under X
// staging). GEMM2 in-place on sH; GEMM3 partials in sX alias; staged coalesced
// atomics. LDS 51.5 KB -> 3 blocks/CU.
__global__ __launch_bounds__(512, 6)
void fused_mlp(const float* __restrict__ X, const int* __restrict__ c2b,
               const int* __restrict__ c2s, const float* __restrict__ b2,
               const float* __restrict__ b3,
               const __hip_bfloat16* __restrict__ w1p,
               const __hip_bfloat16* __restrict__ w2p,
               const __hip_bfloat16* __restrict__ w3p,
               const float* __restrict__ zw1,
               float* __restrict__ accs, float* __restrict__ cnts) {
    __shared__ __align__(16) short sX[M_TILE * LDA];   // Xp; aliased as GEMM3 partials
    __shared__ short sH[M_TILE][LDH];                  // H0 then H1 (in-place)
    __shared__ int sSI[M_TILE];
    short (*xp)[LDA] = (short (*)[LDA])sX;
    float (*sP)[M_TILE][SP_LD] = (float (*)[M_TILE][SP_LD])sX;

    const int tid = threadIdx.x;
    const int w   = tid >> 6;     // wave 0..7
    const int L   = tid & 63;
    const int q   = L >> 4;
    const int ln  = L & 15;
    const int wm  = w >> 2;       // cell-half
    const int wn  = w & 3;        // N-quarter
    const int base = blockIdx.x * M_TILE;

    // ---- GEMM1 C-init: gather ZW1 rows (issued early, hidden under staging) ----
    int g0 = base + wm * 32 + ln;      if (g0 >= N_CELLS) g0 = N_CELLS - 1;
    int g1 = base + wm * 32 + 16 + ln; if (g1 >= N_CELLS) g1 = N_CELLS - 1;
    int cb0 = c2b[g0];
    int cb1 = c2b[g1];
    floatx4 acc[2][4];
#pragma unroll
    for (int nt = 0; nt < 4; ++nt) {
        acc[0][nt] = *(const floatx4*)(zw1 + (size_t)cb0 * H_DIM + wn * 64 + nt * 16 + q * 4);
        acc[1][nt] = *(const floatx4*)(zw1 + (size_t)cb1 * H_DIM + wn * 64 + nt * 16 + q * 4);
    }

    // ---- stage Xp = log2(1+X) as bf16 (K=128 only; Z handled via ZW1) ----
#pragma unroll
    for (int i = 0; i < 4; ++i) {
        int idx = tid + i * 512;          // 64 rows * 32 float4
        int row = idx >> 5, c4 = idx & 31;
        int gr = base + row; if (gr >= N_CELLS) gr = N_CELLS - 1;
        float4 v = *(const float4*)(X + (size_t)gr * D_X + c4 * 4);
        short4v pk;
        pk.x = bfb(__log2f(1.0f + v.x));
        pk.y = bfb(__log2f(1.0f + v.y));
        pk.z = bfb(__log2f(1.0f + v.z));
        pk.w = bfb(__log2f(1.0f + v.w));
        *(short4v*)&xp[row][c4 * 4] = pk;
    }
    if ((tid & 7) == 0) {
        int row = tid >> 3;
        int gr = base + row; if (gr >= N_CELLS) gr = N_CELLS - 1;
        sSI[row] = c2s[gr];
    }
    __syncthreads();                                            // b1

    // ---- GEMM1: relu(logX @ W1x + ZW1) -> sH ----
#pragma unroll
    for (int s = 0; s < 4; ++s) {
        short8 x0 = *(const short8*)&xp[wm * 32 + ln][s * 32 + q * 8];
        short8 x1 = *(const short8*)&xp[wm * 32 + 16 + ln][s * 32 + q * 8];
#pragma unroll
        for (int nt = 0; nt < 4; ++nt) {
            short8 wf = *(const short8*)(w1p + (size_t)(((((wn * 4 + nt) * 4) + s) << 6) + L) * 8);
            acc[0][nt] = __builtin_amdgcn_mfma_f32_16x16x32_bf16(wf, x0, acc[0][nt], 0, 0, 0);
            acc[1][nt] = __builtin_amdgcn_mfma_f32_16x16x32_bf16(wf, x1, acc[1][nt], 0, 0, 0);
        }
    }
#pragma unroll
    for (int nt = 0; nt < 4; ++nt) {
        short4v p0, p1;
        p0.x = bfb(fmaxf(acc[0][nt][0], 0.f));
        p0.y = bfb(fmaxf(acc[0][nt][1], 0.f));
        p0.z = bfb(fmaxf(acc[0][nt][2], 0.f));
        p0.w = bfb(fmaxf(acc[0][nt][3], 0.f));
        p1.x = bfb(fmaxf(acc[1][nt][0], 0.f));
        p1.y = bfb(fmaxf(acc[1][nt][1], 0.f));
        p1.z = bfb(fmaxf(acc[1][nt][2], 0.f));
        p1.w = bfb(fmaxf(acc[1][nt][3], 0.f));
        *(short4v*)&sH[wm * 32 + ln][wn * 64 + nt * 16 + q * 4] = p0;
        *(short4v*)&sH[wm * 32 + 16 + ln][wn * 64 + nt * 16 + q * 4] = p1;
    }
    __syncthreads();                                            // b2

    // ---- GEMM2: relu(H0 @ W2 + b2), in-place on sH ----
#pragma unroll
    for (int nt = 0; nt < 4; ++nt) {
        float4 bv = *(const float4*)(b2 + wn * 64 + nt * 16 + q * 4);
        acc[0][nt] = (floatx4){bv.x, bv.y, bv.z, bv.w};
        acc[1][nt] = acc[0][nt];
    }
#pragma unroll
    for (int s = 0; s < 8; ++s) {
        short8 x0 = *(const short8*)&sH[wm * 32 + ln][s * 32 + q * 8];
        short8 x1 = *(const short8*)&sH[wm * 32 + 16 + ln][s * 32 + q * 8];
#pragma unroll
        for (int nt = 0; nt < 4; ++nt) {
            short8 wf = *(const short8*)(w2p + (size_t)(((((wn * 4 + nt) * 8) + s) << 6) + L) * 8);
            acc[0][nt] = __builtin_amdgcn_mfma_f32_16x16x32_bf16(wf, x0, acc[0][nt], 0, 0, 0);
            acc[1][nt] = __builtin_amdgcn_mfma_f32_16x16x32_bf16(wf, x1, acc[1][nt], 0, 0, 0);
        }
    }
    __syncthreads();                                            // b3: all reads done
#pragma unroll
    for (int nt = 0; nt < 4; ++nt) {
        short4v p0, p1;
        p0.x = bfb(fmaxf(acc[0][nt][0], 0.f));
        p0.y = bfb(fmaxf(acc[0][nt][1], 0.f));
        p0.z = bfb(fmaxf(acc[0][nt][2], 0.f));
        p0.w = bfb(fmaxf(acc[0][nt][3], 0.f));
        p1.x = bfb(fmaxf(acc[1][nt][0], 0.f));
        p1.y = bfb(fmaxf(acc[1][nt][1], 0.f));
        p1.z = bfb(fmaxf(acc[1][nt][2], 0.f));
        p1.w = bfb(fmaxf(acc[1][nt][3], 0.f));
        *(short4v*)&sH[wm * 32 + ln][wn * 64 + nt * 16 + q * 4] = p0;
        *(short4v*)&sH[wm * 32 + 16 + ln][wn * 64 + nt * 16 + q * 4] = p1;
    }
    __syncthreads();                                            // b4

    // ---- GEMM3: 8 waves = 4 cell-groups x 2 K-halves -> sP (sX alias) ----
    {
        int g  = w & 3;
        int kh = w >> 2;
        floatx4 a3 = (floatx4){0.f, 0.f, 0.f, 0.f};
#pragma unroll
        for (int ss = 0; ss < 4; ++ss) {
            int s = kh * 4 + ss;
            short8 hv = *(const short8*)&sH[g * 16 + ln][s * 32 + q * 8];
            short8 wf = *(const short8*)(w3p + (size_t)((s << 6) + L) * 8);
            a3 = __builtin_amdgcn_mfma_f32_16x16x32_bf16(wf, hv, a3, 0, 0, 0);
        }
#pragma unroll
        for (int r = 0; r < 4; ++r)
            sP[kh][g * 16 + ln][q * 4 + r] = a3[r];
    }
    __syncthreads();                                            // b5

    // ---- combine K-halves + b3, staged coalesced atomics ----
    {
        int rep = blockIdx.x & (NREP - 1);
        float* accR = accs + (size_t)rep * (B_SAMP * D_OUT);
#pragma unroll
        for (int i = 0; i < 2; ++i) {
            int idx = tid + i * 512;      // 64 cells x 16 outs
            int m = idx >> 4, n = idx & 15;
            int cell = base + m;
            if (cell < N_CELLS) {
                float v = sP[0][m][n] + sP[1][m][n] + b3[n];
                atomicAdd(&accR[(size_t)sSI[m] * D_OUT + n], v);
            }
        }
    }
}

__global__ __launch_bounds__(256)
void finalize(const float* __restrict__ accs, const float* __restrict__ cnts,
              float* __restrict__ out) {
    int o = blockIdx.x * blockDim.x + threadIdx.x;   // 0..8191
    int s = o >> 4;
    float sum = 0.f, cnt = 0.f;
#pragma unroll 8
    for (int r = 0; r < NREP; ++r) {
        sum += accs[(size_t)r * (B_SAMP * D_OUT) + o];
        cnt += cnts[(size_t)r * B_SAMP + s];
    }
    out[o] = sum / fmaxf(cnt, 1.0f);
}

extern "C" void kernel_launch(void* const* d_in, const int* in_sizes, int n_in,
                              void* d_out, int out_size, void* d_ws, size_t ws_size,
                              hipStream_t stream) {
    const float* X   = (const float*)d_in[0];
    const float* Z   = (const float*)d_in[1];
    const float* W1  = (const float*)d_in[2];
    const float* b1  = (const float*)d_in[3];
    const float* W2  = (const float*)d_in[4];
    const float* b2  = (const float*)d_in[5];
    const float* W3  = (const float*)d_in[6];
    const float* b3  = (const float*)d_in[7];
    const int*   c2b = (const int*)d_in[8];
    const int*   sidx= (const int*)d_in[9];

    char* ws = (char*)d_ws;
    __hip_bfloat16* w1p = (__hip_bfloat16*)(ws + OFF_W1P);
    __hip_bfloat16* w2p = (__hip_bfloat16*)(ws + OFF_W2P);
    __hip_bfloat16* w3p = (__hip_bfloat16*)(ws + OFF_W3P);
    float* zw1  = (float*)(ws + OFF_ZW);
    float* accs = (float*)(ws + OFF_ACC);
    float* cnts = (float*)(ws + OFF_CNT);
    int*   c2s  = (int*)(ws + OFF_C2S);
    float* out  = (float*)d_out;

    // zero accs+cnts (contiguous); stream-ordered, graph-capture-safe
    hipMemsetAsync(accs, 0, (size_t)NREP * (B_SAMP * D_OUT + B_SAMP) * 4, stream);

    prep<<<W1_BLKS + W2_BLKS + W3_BLKS + ZW_BLKS + C2S_BLKS, 256, 0, stream>>>(
        W1, b1, W2, W3, Z, c2b, sidx, w1p, w2p, w3p, zw1, cnts, c2s);

    fused_mlp<<<NBLK, 512, 0, stream>>>(X, c2b, c2s, b2, b3,
                                        w1p, w2p, w3p, zw1, accs, cnts);
    finalize<<<32, 256, 0, stream>>>(accs, cnts, out);
}